// Round 9
// baseline (257.179 us; speedup 1.0000x reference)
//
#include <hip/hip_runtime.h>
#include <stdint.h>

#define NUM_CLASSES 80u
#define TOPK 1000
#define CONF_T 0.05f
#define NMS_T 0.6f
#define MAX_COORD 4096.0f
#define TARGET 1152u            // top-1000 + tie/superset slack
#define CAP 49152u              // candidate buffer capacity (= 48 * 1024)
#define KPT 48                  // keys per thread in kM registers
#define SRVCAP 2048u            // survivor buffer (>= TARGET + boundary ties)
#define NBINS 4096              // fallback coarse bins = key >> 20
#define STATIC_KEY 0xC0800000u  // fkey(+4.0f): static candidate prefilter
#define LCAP 512u               // per-block LDS candidate staging (kA)

typedef unsigned long long ull;
typedef ull ull2 __attribute__((ext_vector_type(2)));

// Monotone float->uint key: descending float == descending key
__device__ __forceinline__ uint32_t fkey(float x) {
  uint32_t k = __float_as_uint(x);
  return (k & 0x80000000u) ? ~k : (k | 0x80000000u);
}

// Inclusive suffix sum across 1024 threads (fallback path only).
__device__ __forceinline__ uint32_t suffix_scan_1024(uint32_t v, uint32_t* part,
                                                     int t) {
  int lane = t & 63, wid = t >> 6;
#pragma unroll
  for (int off = 1; off < 64; off <<= 1) {
    uint32_t x = __shfl_down(v, off);
    if (lane + off < 64) v += x;
  }
  if (lane == 0) part[wid] = v;
  __syncthreads();
  if (wid == 0) {
    uint32_t pv = (lane < 16) ? part[lane] : 0u;
#pragma unroll
    for (int off = 1; off < 16; off <<= 1) {
      uint32_t x = __shfl_down(pv, off);
      if (lane + off < 16) pv += x;
    }
    if (lane < 16) part[lane] = pv;
  }
  __syncthreads();
  uint32_t after = (wid < 15) ? part[wid + 1] : 0u;
  return v + after;
}

// Block-wide sum of v across 1024 threads; result broadcast to all.
// Uses part[0..16]; 2 barriers.
__device__ __forceinline__ uint32_t block_sum_1024(uint32_t v, uint32_t* part,
                                                   int t) {
  int lane = t & 63, wid = t >> 6;
#pragma unroll
  for (int off = 32; off >= 1; off >>= 1) v += __shfl_xor(v, off);
  if (lane == 0) part[wid] = v;
  __syncthreads();
  if (wid == 0 && lane < 16) {
    uint32_t r = part[lane];
#pragma unroll
    for (int off = 8; off >= 1; off >>= 1) r += __shfl_xor(r, off);
    if (lane == 0) part[16] = r;
  }
  __syncthreads();
  return part[16];
}

// ---------------- kernel Z: zero counters (ws poisoned 0xAA) --------------
__global__ void kz(uint32_t* sel) {
  if (threadIdx.x < 16) sel[threadIdx.x] = 0u;
}

// ---------------- kernel A: prefilter + compact (the only full scan) ------
// ~28K candidates (x >= +4.0) staged per-block in LDS, flushed with ONE
// global atomicAdd per block. 84MB read => ~14us floor.
__global__ void __launch_bounds__(256) kA(const float4* __restrict__ cls, int n4,
                                          uint32_t* sel,
                                          uint32_t* candKey, uint32_t* candIdx) {
  __shared__ uint32_t lk[LCAP];
  __shared__ uint32_t li[LCAP];
  __shared__ uint32_t lcnt, gbase;
  if (threadIdx.x == 0) lcnt = 0u;
  __syncthreads();
  int stride = gridDim.x * blockDim.x;
  for (int i = blockIdx.x * blockDim.x + threadIdx.x; i < n4; i += stride) {
    float4 v = cls[i];
    uint32_t k4[4] = {fkey(v.x), fkey(v.y), fkey(v.z), fkey(v.w)};
#pragma unroll
    for (int c = 0; c < 4; ++c) {
      uint32_t k = k4[c];
      if (k >= STATIC_KEY) {
        uint32_t p = atomicAdd(&lcnt, 1u);  // LDS atomic, rare lane
        if (p < LCAP) { lk[p] = k; li[p] = (uint32_t)i * 4u + c; }
        else {  // spill (correctness-only; ~never)
          uint32_t gp = atomicAdd(&sel[2], 1u);
          if (gp < CAP) { candKey[gp] = k; candIdx[gp] = (uint32_t)i * 4u + c; }
        }
      }
    }
  }
  __syncthreads();
  uint32_t c = lcnt; if (c > LCAP) c = LCAP;
  if (threadIdx.x == 0 && c) gbase = atomicAdd(&sel[2], c);  // ONE per block
  __syncthreads();
  for (uint32_t i = threadIdx.x; i < c; i += 256u) {
    uint32_t gp = gbase + i;
    if (gp < CAP) { candKey[gp] = lk[i]; candIdx[gp] = li[i]; }
  }
}

// ---------------- kernel M: threshold (binary search) + rank + emit -------
// Round-8 lesson: coarse histogram of candidates = 28K same-address LDS
// atomics into ~10 hot bins (all keys >= STATIC_KEY) => 78us. Replaced by
// block-wide binary search on the key value: registers + shfl reductions,
// ZERO atomics in the normal path. Histogram survives only in the
// pathological fallback (n < TARGET).
__global__ void __launch_bounds__(1024) kM(
    const float* __restrict__ cls, const float4* __restrict__ cls4, int n4,
    const float* __restrict__ box, const int* __restrict__ ph,
    const int* __restrict__ pw, uint32_t* sel,
    uint32_t* __restrict__ candKey, uint32_t* __restrict__ candIdx,
    float* __restrict__ out, float* __restrict__ topScore,
    float* __restrict__ obox) {
  __shared__ uint32_t ch[NBINS];            // 16 KB (fallback only)
  __shared__ uint32_t part[32];
  __shared__ uint32_t lidx[SRVCAP];         // 8 KB
  __shared__ __align__(16) ull sk[SRVCAP];  // 16 KB
  __shared__ uint32_t scnt, fbS, nS;
  int tid = threadIdx.x;
  uint32_t n = sel[2]; if (n > CAP) n = CAP;
  if (tid == 0) { scnt = 0u; fbS = 0u; }

  if (n < TARGET) {  // ---- FALLBACK (pathological inputs only; slow path)
    for (int i = tid; i < NBINS; i += 1024) ch[i] = 0u;
    __syncthreads();
    for (int i = tid; i < n4; i += 1024) {
      float4 v = cls4[i];
      atomicAdd(&ch[fkey(v.x) >> 20], 1u);
      atomicAdd(&ch[fkey(v.y) >> 20], 1u);
      atomicAdd(&ch[fkey(v.z) >> 20], 1u);
      atomicAdd(&ch[fkey(v.w) >> 20], 1u);
    }
    __syncthreads();
    uint32_t c0 = ch[tid * 4], c1 = ch[tid * 4 + 1];
    uint32_t c2 = ch[tid * 4 + 2], c3 = ch[tid * 4 + 3];
    uint32_t v = c0 + c1 + c2 + c3;
    uint32_t suff = suffix_scan_1024(v, part, tid);
    uint32_t above = suff - v;
    if ((suff >= TARGET) && (above < TARGET)) {
      uint32_t cum = above;
      uint32_t cc[4] = {c0, c1, c2, c3};
      for (int j = 3; j >= 0; --j) {
        if (cum + cc[j] >= TARGET) { fbS = (uint32_t)(tid * 4 + j); break; }
        cum += cc[j];
      }
    }
    __syncthreads();  // fbS stays 0 if total < TARGET => take-all
    uint32_t bsel = fbS;
    for (int i = tid; i < n4; i += 1024) {
      float4 v4 = cls4[i];
      uint32_t k4[4] = {fkey(v4.x), fkey(v4.y), fkey(v4.z), fkey(v4.w)};
#pragma unroll
      for (int c = 0; c < 4; ++c) {
        uint32_t k = k4[c];
        if ((k >> 20) >= bsel && k < STATIC_KEY) {
          uint32_t gp = atomicAdd(&sel[2], 1u);
          if (gp < CAP) { candKey[gp] = k; candIdx[gp] = (uint32_t)i * 4u + c; }
        }
      }
    }
    __syncthreads();
    if (tid == 0) nS = atomicAdd(&sel[2], 0u);  // coherent re-read
    __syncthreads();
    n = nS; if (n > CAP) n = CAP;
  }

  // ---- load candidate keys into registers (coalesced; pad with 0)
  uint32_t keys[KPT];
#pragma unroll
  for (int j = 0; j < KPT; ++j) {
    uint32_t idx = (uint32_t)tid + 1024u * (uint32_t)j;
    keys[j] = (idx < n) ? candKey[idx] : 0u;
  }

  // ---- binary search for T = max{T : count(key >= T) >= TARGET}
  uint32_t T = 0u;
  if (n >= TARGET) {
    uint32_t lo = 0u, hi = 0xFFFFFFFFu;
    while (lo < hi) {  // uniform across block; <= 33 iterations
      uint32_t mid = lo + ((hi - lo) >> 1) + 1u;  // in (lo, hi], no overflow
      uint32_t c = 0u;
#pragma unroll
      for (int j = 0; j < KPT; ++j) c += (keys[j] >= mid) ? 1u : 0u;
      uint32_t total = block_sum_1024(c, part, tid);  // pad-0 never counted
      if (total >= TARGET) lo = mid; else hi = mid - 1u;
    }
    T = lo;
  }

  // ---- select survivors (small LDS atomic traffic: ~TARGET hits)
#pragma unroll
  for (int j = 0; j < KPT; ++j) {
    uint32_t idx = (uint32_t)tid + 1024u * (uint32_t)j;
    if (idx < n && keys[j] >= T) {
      uint32_t pos = atomicAdd(&scnt, 1u);
      if (pos < SRVCAP) lidx[pos] = candIdx[idx];
    }
  }
  __syncthreads();
  uint32_t c = scnt; if (c > SRVCAP) c = SRVCAP;
  uint32_t pad = (c + 1u) & ~1u;

  // ---- sigmoid + key build (np fp32: 1/(1+exp(-x)); ties -> lower idx)
  for (uint32_t i = tid; i < pad; i += 1024u) {
    if (i < c) {
      uint32_t idx = lidx[i];
      float x = cls[idx];
      float p = 1.0f / (1.0f + expf(-x));
      sk[i] = ((ull)__float_as_uint(p) << 32) | (ull)(uint32_t)(~idx);
    } else sk[i] = 0ull;
  }
  // prefill outputs (degenerate scount < 1000 safety)
  for (int i = tid; i < 4000; i += 1024) { out[i] = 0.0f; obox[i] = 0.0f; }
  for (int i = tid; i < 1000; i += 1024) { out[5000 + i] = 0.0f; topScore[i] = 0.0f; }
  __syncthreads();

  // ---- rank + emit: rank_i = #{j: sk[j] > sk[i]} (keys unique => exact)
  for (uint32_t i = tid; i < c; i += 1024u) {
    ull my = sk[i];
    uint32_t rank = 0;
#pragma unroll 4
    for (uint32_t j = 0; j < pad; j += 2u) {
      ull2 w = *reinterpret_cast<const ull2*>(&sk[j]);  // broadcast b128 read
      rank += (w.x > my) + (w.y > my);
    }
    if (rank >= TOPK) continue;
    uint32_t idx = ~(uint32_t)my;
    float p = __uint_as_float((uint32_t)(my >> 32));
    uint32_t label = idx % NUM_CLASSES;
    uint32_t anchor = idx / NUM_CLASSES;
    float W = (float)pw[0], H = (float)ph[0];
    float b0 = box[anchor * 4u + 0u], b1 = box[anchor * 4u + 1u];
    float b2 = box[anchor * 4u + 2u], b3 = box[anchor * 4u + 3u];
    out[rank * 4 + 0] = fminf(fmaxf(b0 / W, 0.0f), 1.0f);
    out[rank * 4 + 1] = fminf(fmaxf(b1 / H, 0.0f), 1.0f);
    out[rank * 4 + 2] = fminf(fmaxf(b2 / W, 0.0f), 1.0f);
    out[rank * 4 + 3] = fminf(fmaxf(b3 / H, 0.0f), 1.0f);
    out[5000 + rank] = (float)label;
    topScore[rank] = p;
    float off = (float)label * MAX_COORD;  // class-aware NMS offset
    obox[rank * 4 + 0] = b0 + off; obox[rank * 4 + 1] = b1 + off;
    obox[rank * 4 + 2] = b2 + off; obox[rank * 4 + 3] = b3 + off;
  }
}

// ---------------- kernel G: IoU suppression bitmasks (j > i) --------------
// Kept multi-block: 1M-pair IoU is ~12M VALU ops => ~39us on one CU but
// ~5us across 1000 blocks. Do NOT fuse into kM/kH.
__global__ void kG(const float* __restrict__ obox, ull* __restrict__ masks) {
  int i = blockIdx.x;  // row 0..999
  float x1i = obox[i * 4 + 0], y1i = obox[i * 4 + 1];
  float x2i = obox[i * 4 + 2], y2i = obox[i * 4 + 3];
  float ai = (x2i - x1i) * (y2i - y1i);
  for (int base = 0; base < 1024; base += 256) {
    int jj = base + (int)threadIdx.x;
    bool bit = false;
    if (jj < TOPK && jj > i) {
      float x1j = obox[jj * 4 + 0], y1j = obox[jj * 4 + 1];
      float x2j = obox[jj * 4 + 2], y2j = obox[jj * 4 + 3];
      float aj = (x2j - x1j) * (y2j - y1j);
      float ix1 = fmaxf(x1i, x1j), iy1 = fmaxf(y1i, y1j);
      float ix2 = fminf(x2i, x2j), iy2 = fminf(y2i, y2j);
      float iw = fmaxf(ix2 - ix1, 0.0f), ih = fmaxf(iy2 - iy1, 0.0f);
      float inter = iw * ih;
      float iou = inter / (ai + aj - inter + 1e-9f);
      bit = iou > NMS_T;
    }
    ull m = __ballot(bit);
    if ((threadIdx.x & 63u) == 0u) masks[i * 16 + (jj >> 6)] = m;
  }
}

// ---------------- kernel H: LDS-staged single-wave greedy NMS -------------
__global__ void __launch_bounds__(256) kH(const float* __restrict__ topScore,
                                          const ull* __restrict__ masks,
                                          float* __restrict__ out) {
  __shared__ ull lmask[TOPK * 16];
  __shared__ uint32_t nzrow[TOPK];
  __shared__ ull keepsh[16];
  int t = threadIdx.x;
  for (int i = t; i < TOPK; i += 256) nzrow[i] = 0u;
  if (t < 16) keepsh[t] = 0ull;
  __syncthreads();
  for (int i = t; i < TOPK * 16; i += 256) {
    ull m = masks[i];
    lmask[i] = m;
    if (m) atomicOr(&nzrow[i >> 4], 1u);
  }
  for (int base = 0; base < 1024; base += 256) {
    int r = base + t;
    bool v = (r < TOPK) && (topScore[r] > CONF_T);
    ull b = __ballot(v);
    if ((t & 63) == 0) keepsh[(base >> 6) + (t >> 6)] = b;
  }
  __syncthreads();
  if (t < 64) {  // single-wave greedy loop, no barriers inside
    ull kw = (t < 16) ? keepsh[t] : 0ull;
    ull nzw = 0ull;
    if (t < 16) {
      for (int b = 0; b < 64; ++b) {
        int r = t * 64 + b;
        if (r < TOPK && nzrow[r]) nzw |= 1ull << b;
      }
    }
    for (int w = 0; w < 16; ++w) {
      ull cur = __shfl(kw, w) & __shfl(nzw, w);
      while (cur) {
        int b = __ffsll((long long)cur) - 1;
        int i = w * 64 + b;
        if (t < 16) kw &= ~lmask[i * 16 + t];  // row i suppresses only j > i
        ull nk = __shfl(kw, w);
        cur = nk & __shfl(nzw, w);
        cur &= (b == 63) ? 0ull : (~0ull << (b + 1));
      }
    }
    if (t < 16) keepsh[t] = kw;
  }
  __syncthreads();
  for (int r = t; r < TOPK; r += 256) {
    bool k = (keepsh[r >> 6] >> (r & 63)) & 1ull;
    float s = topScore[r];
    out[4000 + r] = k ? s : 0.0f;
    out[6000 + r] = k ? 1.0f : 0.0f;
  }
}

extern "C" void kernel_launch(void* const* d_in, const int* in_sizes, int n_in,
                              void* d_out, int out_size, void* d_ws, size_t ws_size,
                              hipStream_t stream) {
  const float* cls = (const float*)d_in[0];  // (1, N, 80) logits
  const float* box = (const float*)d_in[1];  // (1, N, 4)
  const int* ph = (const int*)d_in[2];       // img_h
  const int* pw = (const int*)d_in[3];       // img_w
  float* out = (float*)d_out;                // [boxes 4000 | scores 1000 | labels 1000 | keep 1000]
  int n = in_sizes[0];                       // 20,971,520 (divisible by 4)

  uint8_t* w = (uint8_t*)d_ws;
  uint32_t* sel     = (uint32_t*)(w);                            // 64 B
  uint32_t* candKey = (uint32_t*)(w + 4096);                     // 192 KB
  uint32_t* candIdx = (uint32_t*)(w + 4096 + (size_t)CAP * 4);   // 192 KB
  float*    topScore= (float*)   (w + 4096 + (size_t)CAP * 8);           // 4 KB
  float*    obox    = (float*)   (w + 4096 + (size_t)CAP * 8 + 4096);    // 16 KB
  ull*      masks   = (ull*)     (w + 4096 + (size_t)CAP * 8 + 4096 + 16384); // 125 KB

  kz<<<1, 64, 0, stream>>>(sel);
  kA<<<2048, 256, 0, stream>>>((const float4*)cls, n / 4, sel, candKey, candIdx);
  kM<<<1, 1024, 0, stream>>>(cls, (const float4*)cls, n / 4, box, ph, pw,
                             sel, candKey, candIdx, out, topScore, obox);
  kG<<<TOPK, 256, 0, stream>>>(obox, masks);
  kH<<<1, 256, 0, stream>>>(topScore, masks, out);
}

// Round 10
// 235.720 us; speedup vs baseline: 1.0910x; 1.0910x over previous
//
#include <hip/hip_runtime.h>
#include <stdint.h>

#define NUM_CLASSES 80u
#define TOPK 1000
#define CONF_T 0.05f
#define NMS_T 0.6f
#define MAX_COORD 4096.0f
#define TARGET 1152u            // top-1000 + tie/superset slack
#define CAP 49152u              // candidate buffer capacity (= 48 * 1024)
#define KPT 48                  // keys per thread in kT registers
#define SRVCAP 2048u            // survivor buffer (>= TARGET + window slack)
#define NBINS 4096              // fallback coarse bins = key >> 20
#define STATIC_KEY 0xC0800000u  // fkey(+4.0f): static candidate prefilter
#define LCAP 512u               // per-block LDS candidate staging (kA)

typedef unsigned long long ull;
typedef ull ull2 __attribute__((ext_vector_type(2)));

// Monotone float->uint key: descending float == descending key
__device__ __forceinline__ uint32_t fkey(float x) {
  uint32_t k = __float_as_uint(x);
  return (k & 0x80000000u) ? ~k : (k | 0x80000000u);
}

// Inclusive suffix sum across 1024 threads (fallback path only).
__device__ __forceinline__ uint32_t suffix_scan_1024(uint32_t v, uint32_t* part,
                                                     int t) {
  int lane = t & 63, wid = t >> 6;
#pragma unroll
  for (int off = 1; off < 64; off <<= 1) {
    uint32_t x = __shfl_down(v, off);
    if (lane + off < 64) v += x;
  }
  if (lane == 0) part[wid] = v;
  __syncthreads();
  if (wid == 0) {
    uint32_t pv = (lane < 16) ? part[lane] : 0u;
#pragma unroll
    for (int off = 1; off < 16; off <<= 1) {
      uint32_t x = __shfl_down(pv, off);
      if (lane + off < 16) pv += x;
    }
    if (lane < 16) part[lane] = pv;
  }
  __syncthreads();
  uint32_t after = (wid < 15) ? part[wid + 1] : 0u;
  return v + after;
}

// Block-wide sum of v across 1024 threads; result broadcast to all.
__device__ __forceinline__ uint32_t block_sum_1024(uint32_t v, uint32_t* part,
                                                   int t) {
  int lane = t & 63, wid = t >> 6;
#pragma unroll
  for (int off = 32; off >= 1; off >>= 1) v += __shfl_xor(v, off);
  if (lane == 0) part[wid] = v;
  __syncthreads();
  if (wid == 0 && lane < 16) {
    uint32_t r = part[lane];
#pragma unroll
    for (int off = 8; off >= 1; off >>= 1) r += __shfl_xor(r, off);
    if (lane == 0) part[16] = r;
  }
  __syncthreads();
  return part[16];
}

// ---------------- kernel Z: zero counters (ws poisoned 0xAA) --------------
__global__ void kz(uint32_t* sel) {
  if (threadIdx.x < 16) sel[threadIdx.x] = 0u;
}

// ---------------- kernel A: prefilter + compact (the only full scan) ------
__global__ void __launch_bounds__(256) kA(const float4* __restrict__ cls, int n4,
                                          uint32_t* sel,
                                          uint32_t* candKey, uint32_t* candIdx) {
  __shared__ uint32_t lk[LCAP];
  __shared__ uint32_t li[LCAP];
  __shared__ uint32_t lcnt, gbase;
  if (threadIdx.x == 0) lcnt = 0u;
  __syncthreads();
  int stride = gridDim.x * blockDim.x;
  for (int i = blockIdx.x * blockDim.x + threadIdx.x; i < n4; i += stride) {
    float4 v = cls[i];
    uint32_t k4[4] = {fkey(v.x), fkey(v.y), fkey(v.z), fkey(v.w)};
#pragma unroll
    for (int c = 0; c < 4; ++c) {
      uint32_t k = k4[c];
      if (k >= STATIC_KEY) {
        uint32_t p = atomicAdd(&lcnt, 1u);  // LDS atomic, rare lane
        if (p < LCAP) { lk[p] = k; li[p] = (uint32_t)i * 4u + c; }
        else {  // spill (correctness-only; ~never)
          uint32_t gp = atomicAdd(&sel[2], 1u);
          if (gp < CAP) { candKey[gp] = k; candIdx[gp] = (uint32_t)i * 4u + c; }
        }
      }
    }
  }
  __syncthreads();
  uint32_t c = lcnt; if (c > LCAP) c = LCAP;
  if (threadIdx.x == 0 && c) gbase = atomicAdd(&sel[2], c);  // ONE per block
  __syncthreads();
  for (uint32_t i = threadIdx.x; i < c; i += 256u) {
    uint32_t gp = gbase + i;
    if (gp < CAP) { candKey[gp] = lk[i]; candIdx[gp] = li[i]; }
  }
}

// ---------------- kernel T: threshold (20-bit binary search) + select -----
// Single block. Round-9 lesson: do NOT fuse the O(n^2) rank here — single-CU
// LDS serialization cost 30-50us; rank lives in kR across 32 CUs. Threshold
// search on top-20 key bits only (20 iters, granularity 4096 key values;
// boundary-window over-collection ~tens of keys, absorbed by SRVCAP).
__global__ void __launch_bounds__(1024) kT(
    const float* __restrict__ cls, const float4* __restrict__ cls4, int n4,
    uint32_t* sel, uint32_t* __restrict__ candKey,
    uint32_t* __restrict__ candIdx, ull* __restrict__ srv,
    float* __restrict__ out, float* __restrict__ topScore,
    float* __restrict__ obox) {
  __shared__ uint32_t ch[NBINS];     // 16 KB (fallback only)
  __shared__ uint32_t part[32];
  __shared__ uint32_t lidx[SRVCAP];  // 8 KB
  __shared__ uint32_t scnt, fbS, nS;
  int tid = threadIdx.x;
  uint32_t n = sel[2]; if (n > CAP) n = CAP;
  if (tid == 0) { scnt = 0u; fbS = 0u; }

  if (n < TARGET) {  // ---- FALLBACK (pathological inputs only; slow path)
    for (int i = tid; i < NBINS; i += 1024) ch[i] = 0u;
    __syncthreads();
    for (int i = tid; i < n4; i += 1024) {
      float4 v = cls4[i];
      atomicAdd(&ch[fkey(v.x) >> 20], 1u);
      atomicAdd(&ch[fkey(v.y) >> 20], 1u);
      atomicAdd(&ch[fkey(v.z) >> 20], 1u);
      atomicAdd(&ch[fkey(v.w) >> 20], 1u);
    }
    __syncthreads();
    uint32_t c0 = ch[tid * 4], c1 = ch[tid * 4 + 1];
    uint32_t c2 = ch[tid * 4 + 2], c3 = ch[tid * 4 + 3];
    uint32_t v = c0 + c1 + c2 + c3;
    uint32_t suff = suffix_scan_1024(v, part, tid);
    uint32_t above = suff - v;
    if ((suff >= TARGET) && (above < TARGET)) {
      uint32_t cum = above;
      uint32_t cc[4] = {c0, c1, c2, c3};
      for (int j = 3; j >= 0; --j) {
        if (cum + cc[j] >= TARGET) { fbS = (uint32_t)(tid * 4 + j); break; }
        cum += cc[j];
      }
    }
    __syncthreads();  // fbS stays 0 if total < TARGET => take-all
    uint32_t bsel = fbS;
    for (int i = tid; i < n4; i += 1024) {
      float4 v4 = cls4[i];
      uint32_t k4[4] = {fkey(v4.x), fkey(v4.y), fkey(v4.z), fkey(v4.w)};
#pragma unroll
      for (int c = 0; c < 4; ++c) {
        uint32_t k = k4[c];
        if ((k >> 20) >= bsel && k < STATIC_KEY) {
          uint32_t gp = atomicAdd(&sel[2], 1u);
          if (gp < CAP) { candKey[gp] = k; candIdx[gp] = (uint32_t)i * 4u + c; }
        }
      }
    }
    __syncthreads();
    if (tid == 0) nS = atomicAdd(&sel[2], 0u);  // coherent re-read
    __syncthreads();
    n = nS; if (n > CAP) n = CAP;
  }

  // ---- load candidate keys into registers (coalesced; pad with 0)
  uint32_t keys[KPT];
#pragma unroll
  for (int j = 0; j < KPT; ++j) {
    uint32_t idx = (uint32_t)tid + 1024u * (uint32_t)j;
    keys[j] = (idx < n) ? candKey[idx] : 0u;
  }

  // ---- binary search top-20 bits: T20 = max{m : count(key>>12 >= m) >= TARGET}
  uint32_t T = 0u;
  if (n >= TARGET) {
    uint32_t lo = 0u, hi = 0xFFFFFu;
    while (lo < hi) {  // uniform across block; 20 iterations
      uint32_t mid = lo + ((hi - lo) >> 1) + 1u;
      uint32_t c = 0u;
#pragma unroll
      for (int j = 0; j < KPT; ++j) c += ((keys[j] >> 12) >= mid) ? 1u : 0u;
      uint32_t total = block_sum_1024(c, part, tid);  // pad-0 never counted
      if (total >= TARGET) lo = mid; else hi = mid - 1u;
    }
    T = lo << 12;
  }

  // ---- select survivors (small LDS atomic traffic: ~1200 hits)
#pragma unroll
  for (int j = 0; j < KPT; ++j) {
    uint32_t idx = (uint32_t)tid + 1024u * (uint32_t)j;
    if (idx < n && keys[j] >= T) {
      uint32_t pos = atomicAdd(&scnt, 1u);
      if (pos < SRVCAP) lidx[pos] = candIdx[idx];
    }
  }
  __syncthreads();
  uint32_t c = scnt; if (c > SRVCAP) c = SRVCAP;
  if (tid == 0) sel[4] = c;

  // ---- sigmoid + key build (np fp32: 1/(1+exp(-x)); ties -> lower idx)
  for (uint32_t i = tid; i < c; i += 1024u) {
    uint32_t idx = lidx[i];
    float x = cls[idx];
    float p = 1.0f / (1.0f + expf(-x));
    srv[i] = ((ull)__float_as_uint(p) << 32) | (ull)(uint32_t)(~idx);
  }
  // prefill outputs (degenerate scount < 1000 safety)
  for (int i = tid; i < 4000; i += 1024) { out[i] = 0.0f; obox[i] = 0.0f; }
  for (int i = tid; i < 1000; i += 1024) { out[5000 + i] = 0.0f; topScore[i] = 0.0f; }
}

// ---------------- kernel R: rank survivors + emit (32 blocks x 64) --------
// Thread i ranks survivor i against all staged keys (broadcast b128 LDS
// reads); rank is exact (composite keys unique). ~1.5us/block, parallel.
__global__ void __launch_bounds__(64) kR(
    const float* __restrict__ box, const int* __restrict__ ph,
    const int* __restrict__ pw, const uint32_t* __restrict__ sel,
    const ull* __restrict__ srv, float* __restrict__ out,
    float* __restrict__ topScore, float* __restrict__ obox) {
  __shared__ __align__(16) ull sk[SRVCAP];
  int t = threadIdx.x;
  uint32_t scount = sel[4]; if (scount > SRVCAP) scount = SRVCAP;
  uint32_t pad = (scount + 1u) & ~1u;
  for (uint32_t i = t; i < pad; i += 64u) sk[i] = (i < scount) ? srv[i] : 0ull;
  __syncthreads();
  uint32_t i = blockIdx.x * 64u + (uint32_t)t;
  if (i >= scount) return;
  ull my = sk[i];
  uint32_t rank = 0;
#pragma unroll 4
  for (uint32_t j = 0; j < pad; j += 2u) {
    ull2 v = *reinterpret_cast<const ull2*>(&sk[j]);  // broadcast b128 read
    rank += (v.x > my) + (v.y > my);
  }
  if (rank >= TOPK) return;
  uint32_t idx = ~(uint32_t)my;
  float p = __uint_as_float((uint32_t)(my >> 32));
  uint32_t label = idx % NUM_CLASSES;
  uint32_t anchor = idx / NUM_CLASSES;
  float W = (float)pw[0], H = (float)ph[0];
  float b0 = box[anchor * 4u + 0u], b1 = box[anchor * 4u + 1u];
  float b2 = box[anchor * 4u + 2u], b3 = box[anchor * 4u + 3u];
  out[rank * 4 + 0] = fminf(fmaxf(b0 / W, 0.0f), 1.0f);
  out[rank * 4 + 1] = fminf(fmaxf(b1 / H, 0.0f), 1.0f);
  out[rank * 4 + 2] = fminf(fmaxf(b2 / W, 0.0f), 1.0f);
  out[rank * 4 + 3] = fminf(fmaxf(b3 / H, 0.0f), 1.0f);
  out[5000 + rank] = (float)label;
  topScore[rank] = p;
  float off = (float)label * MAX_COORD;  // class-aware NMS offset
  obox[rank * 4 + 0] = b0 + off; obox[rank * 4 + 1] = b1 + off;
  obox[rank * 4 + 2] = b2 + off; obox[rank * 4 + 3] = b3 + off;
}

// ---------------- kernel G: IoU suppression bitmasks (j > i) --------------
__global__ void kG(const float* __restrict__ obox, ull* __restrict__ masks) {
  int i = blockIdx.x;  // row 0..999
  float x1i = obox[i * 4 + 0], y1i = obox[i * 4 + 1];
  float x2i = obox[i * 4 + 2], y2i = obox[i * 4 + 3];
  float ai = (x2i - x1i) * (y2i - y1i);
  for (int base = 0; base < 1024; base += 256) {
    int jj = base + (int)threadIdx.x;
    bool bit = false;
    if (jj < TOPK && jj > i) {
      float x1j = obox[jj * 4 + 0], y1j = obox[jj * 4 + 1];
      float x2j = obox[jj * 4 + 2], y2j = obox[jj * 4 + 3];
      float aj = (x2j - x1j) * (y2j - y1j);
      float ix1 = fmaxf(x1i, x1j), iy1 = fmaxf(y1i, y1j);
      float ix2 = fminf(x2i, x2j), iy2 = fminf(y2i, y2j);
      float iw = fmaxf(ix2 - ix1, 0.0f), ih = fmaxf(iy2 - iy1, 0.0f);
      float inter = iw * ih;
      float iou = inter / (ai + aj - inter + 1e-9f);
      bit = iou > NMS_T;
    }
    ull m = __ballot(bit);
    if ((threadIdx.x & 63u) == 0u) masks[i * 16 + (jj >> 6)] = m;
  }
}

// ---------------- kernel H: LDS-staged single-wave greedy NMS -------------
__global__ void __launch_bounds__(256) kH(const float* __restrict__ topScore,
                                          const ull* __restrict__ masks,
                                          float* __restrict__ out) {
  __shared__ ull lmask[TOPK * 16];
  __shared__ uint32_t nzrow[TOPK];
  __shared__ ull keepsh[16];
  int t = threadIdx.x;
  for (int i = t; i < TOPK; i += 256) nzrow[i] = 0u;
  if (t < 16) keepsh[t] = 0ull;
  __syncthreads();
  for (int i = t; i < TOPK * 16; i += 256) {
    ull m = masks[i];
    lmask[i] = m;
    if (m) atomicOr(&nzrow[i >> 4], 1u);
  }
  for (int base = 0; base < 1024; base += 256) {
    int r = base + t;
    bool v = (r < TOPK) && (topScore[r] > CONF_T);
    ull b = __ballot(v);
    if ((t & 63) == 0) keepsh[(base >> 6) + (t >> 6)] = b;
  }
  __syncthreads();
  if (t < 64) {  // single-wave greedy loop, no barriers inside
    ull kw = (t < 16) ? keepsh[t] : 0ull;
    ull nzw = 0ull;
    if (t < 16) {
      for (int b = 0; b < 64; ++b) {
        int r = t * 64 + b;
        if (r < TOPK && nzrow[r]) nzw |= 1ull << b;
      }
    }
    for (int w = 0; w < 16; ++w) {
      ull cur = __shfl(kw, w) & __shfl(nzw, w);
      while (cur) {
        int b = __ffsll((long long)cur) - 1;
        int i = w * 64 + b;
        if (t < 16) kw &= ~lmask[i * 16 + t];  // row i suppresses only j > i
        ull nk = __shfl(kw, w);
        cur = nk & __shfl(nzw, w);
        cur &= (b == 63) ? 0ull : (~0ull << (b + 1));
      }
    }
    if (t < 16) keepsh[t] = kw;
  }
  __syncthreads();
  for (int r = t; r < TOPK; r += 256) {
    bool k = (keepsh[r >> 6] >> (r & 63)) & 1ull;
    float s = topScore[r];
    out[4000 + r] = k ? s : 0.0f;
    out[6000 + r] = k ? 1.0f : 0.0f;
  }
}

extern "C" void kernel_launch(void* const* d_in, const int* in_sizes, int n_in,
                              void* d_out, int out_size, void* d_ws, size_t ws_size,
                              hipStream_t stream) {
  const float* cls = (const float*)d_in[0];  // (1, N, 80) logits
  const float* box = (const float*)d_in[1];  // (1, N, 4)
  const int* ph = (const int*)d_in[2];       // img_h
  const int* pw = (const int*)d_in[3];       // img_w
  float* out = (float*)d_out;                // [boxes 4000 | scores 1000 | labels 1000 | keep 1000]
  int n = in_sizes[0];                       // 20,971,520 (divisible by 4)

  uint8_t* w = (uint8_t*)d_ws;
  uint32_t* sel     = (uint32_t*)(w);                            // 64 B
  uint32_t* candKey = (uint32_t*)(w + 4096);                     // 192 KB
  uint32_t* candIdx = (uint32_t*)(w + 4096 + (size_t)CAP * 4);   // 192 KB
  ull*      srv     = (ull*)     (w + 4096 + (size_t)CAP * 8);   // 16 KB
  float*    topScore= (float*)   (w + 4096 + (size_t)CAP * 8 + 16384);        // 4 KB
  float*    obox    = (float*)   (w + 4096 + (size_t)CAP * 8 + 16384 + 4096); // 16 KB
  ull*      masks   = (ull*)     (w + 4096 + (size_t)CAP * 8 + 16384 + 4096 + 16384); // 125 KB

  kz<<<1, 64, 0, stream>>>(sel);
  kA<<<2048, 256, 0, stream>>>((const float4*)cls, n / 4, sel, candKey, candIdx);
  kT<<<1, 1024, 0, stream>>>(cls, (const float4*)cls, n / 4, sel,
                             candKey, candIdx, srv, out, topScore, obox);
  kR<<<SRVCAP / 64, 64, 0, stream>>>(box, ph, pw, sel, srv, out, topScore, obox);
  kG<<<TOPK, 256, 0, stream>>>(obox, masks);
  kH<<<1, 256, 0, stream>>>(topScore, masks, out);
}